// Round 1
// baseline (10874.037 us; speedup 1.0000x reference)
//
#include <hip/hip_runtime.h>

#define N_NODES 100000
#define N_EDGES 3200000
#define F 256

#define BM 128
#define BN 128
#define BK 32

typedef __attribute__((ext_vector_type(8))) short short8;
typedef __attribute__((ext_vector_type(4))) float f32x4;

__device__ inline unsigned short f2bf(float f) {
    // round-to-nearest-even fp32 -> bf16 (inputs are finite, skip NaN path)
    unsigned int u = __float_as_uint(f);
    unsigned int r = (u + 0x7fffu + ((u >> 16) & 1u)) >> 16;
    return (unsigned short)r;
}

// ---------------------------------------------------------------------------
// Weight transpose + convert: Wt[n][k] = bf16(W[k][n]). 256x256, tiny.
// ---------------------------------------------------------------------------
__global__ void wt_kernel(const float* __restrict__ W, unsigned short* __restrict__ Wt) {
    int idx = blockIdx.x * 256 + threadIdx.x;   // 0..65535
    int n = idx >> 8;
    int k = idx & 255;
    Wt[n * 256 + k] = f2bf(W[k * 256 + n]);
}

// ---------------------------------------------------------------------------
// GEMM: out[n, 0:256] = input[n, :] @ W   (bf16 MFMA, fp32 accumulate)
// A: [N_NODES][256] fp32 (converted to bf16 during LDS staging)
// Wt: [256][256] bf16, [n][k] layout (k contiguous -> B frag reads contiguous)
// out: [N_NODES][512] fp32, writes columns 0..255
// grid: (ceil(N_NODES/128), 2), block 256 (4 waves, 2x2; each wave 64x64)
// ---------------------------------------------------------------------------
__global__ __launch_bounds__(256, 2)
void gemm_kernel(const float* __restrict__ A,
                 const unsigned short* __restrict__ Wt,
                 float* __restrict__ out)
{
    __shared__ unsigned short As[BM * BK];  // 8 KB
    __shared__ unsigned short Bs[BN * BK];  // 8 KB, Bs[n][k]

    const int tid   = threadIdx.x;
    const int lane  = tid & 63;
    const int wave  = tid >> 6;
    const int waveM = wave >> 1;  // 0..1
    const int waveN = wave & 1;   // 0..1
    const int rowBase = blockIdx.x * BM;
    const int bn      = blockIdx.y;          // 0..1

    f32x4 acc[4][4];
#pragma unroll
    for (int i = 0; i < 4; i++)
#pragma unroll
        for (int j = 0; j < 4; j++) acc[i][j] = (f32x4)0.0f;

    const int sr = tid >> 2;        // staging row within 64-row round
    const int sk = (tid & 3) * 8;   // staging k offset (8 elems = 16B)

    const int quad = lane >> 4;     // 0..3
    const int l16  = lane & 15;

    for (int kt = 0; kt < 8; kt++) {
        const int k0 = kt * BK;
        // ---- stage A (fp32 -> bf16) and B (bf16 copy), 2 rounds of 64 rows
#pragma unroll
        for (int p = 0; p < 2; p++) {
            const int r = p * 64 + sr;
            const int grow = rowBase + r;
            short8 av;
            if (grow < N_NODES) {
                const float4* pa = (const float4*)(A + (size_t)grow * 256 + k0 + sk);
                float4 f0 = pa[0];
                float4 f1 = pa[1];
                av[0] = (short)f2bf(f0.x); av[1] = (short)f2bf(f0.y);
                av[2] = (short)f2bf(f0.z); av[3] = (short)f2bf(f0.w);
                av[4] = (short)f2bf(f1.x); av[5] = (short)f2bf(f1.y);
                av[6] = (short)f2bf(f1.z); av[7] = (short)f2bf(f1.w);
            } else {
                av = (short8)0;
            }
            *(short8*)(&As[r * BK + sk]) = av;

            const uint4 wv = *(const uint4*)(Wt + (size_t)(bn * BN + r) * 256 + k0 + sk);
            *(uint4*)(&Bs[r * BK + sk]) = wv;
        }
        __syncthreads();

        // ---- fragment loads + 16 MFMAs
        short8 af[4], bfr[4];
#pragma unroll
        for (int i = 0; i < 4; i++)
            af[i] = *(const short8*)(&As[(waveM * 64 + i * 16 + l16) * BK + quad * 8]);
#pragma unroll
        for (int j = 0; j < 4; j++)
            bfr[j] = *(const short8*)(&Bs[(waveN * 64 + j * 16 + l16) * BK + quad * 8]);
#pragma unroll
        for (int i = 0; i < 4; i++)
#pragma unroll
            for (int j = 0; j < 4; j++)
                acc[i][j] = __builtin_amdgcn_mfma_f32_16x16x32_bf16(
                    af[i], bfr[j], acc[i][j], 0, 0, 0);
        __syncthreads();
    }

    // ---- epilogue: C layout col=lane&15, row=(lane>>4)*4+reg
    const int colBase = bn * BN + waveN * 64;
#pragma unroll
    for (int i = 0; i < 4; i++) {
        const int row0 = rowBase + waveM * 64 + i * 16 + quad * 4;
#pragma unroll
        for (int j = 0; j < 4; j++) {
            const int col = colBase + j * 16 + l16;
#pragma unroll
            for (int r = 0; r < 4; r++) {
                const int row = row0 + r;
                if (row < N_NODES)
                    out[(size_t)row * 512 + col] = acc[i][j][r];
            }
        }
    }
}

// ---------------------------------------------------------------------------
// Scatter: out[dst, 256:512] += val * out[src, 0:256]
// (valid because (val*input[src]) summed then @W  ==  sum of val*(input@W)[src])
// One wave per edge: lane reads float4 of the source row, 4 atomicAdds.
// ---------------------------------------------------------------------------
__global__ __launch_bounds__(256)
void scatter_kernel(const int* __restrict__ src, const int* __restrict__ dst,
                    const float* __restrict__ val, float* out)
{
    const int e = blockIdx.x * 4 + (threadIdx.x >> 6);
    if (e >= N_EDGES) return;
    const int lane = threadIdx.x & 63;

    const int s = src[e];
    const int d = dst[e];
    const float v = val[e];

    const float4* xr = (const float4*)(out + (size_t)s * 512);
    float4 x = xr[lane];

    float* w = out + (size_t)d * 512 + 256 + lane * 4;
    atomicAdd(w + 0, v * x.x);
    atomicAdd(w + 1, v * x.y);
    atomicAdd(w + 2, v * x.z);
    atomicAdd(w + 3, v * x.w);
}

// ---------------------------------------------------------------------------
extern "C" void kernel_launch(void* const* d_in, const int* in_sizes, int n_in,
                              void* d_out, int out_size, void* d_ws, size_t ws_size,
                              hipStream_t stream)
{
    const float* input = (const float*)d_in[0];
    const int*   esrc  = (const int*)d_in[1];
    const int*   edst  = (const int*)d_in[2];
    const float* eval  = (const float*)d_in[3];
    const float* W     = (const float*)d_in[4];
    float* out = (float*)d_out;

    unsigned short* Wt = (unsigned short*)d_ws;  // 128 KB of workspace

    // zero entire output (second half accumulates via atomics; first half is
    // overwritten by the GEMM)
    hipMemsetAsync(out, 0, (size_t)N_NODES * 512 * sizeof(float), stream);

    wt_kernel<<<256, 256, 0, stream>>>(W, Wt);

    dim3 g((N_NODES + BM - 1) / BM, 2);
    gemm_kernel<<<g, 256, 0, stream>>>(input, Wt, out);

    scatter_kernel<<<(N_EDGES + 3) / 4, 256, 0, stream>>>(esrc, edst, eval, out);
}

// Round 2
// 1087.354 us; speedup vs baseline: 10.0005x; 10.0005x over previous
//
#include <hip/hip_runtime.h>

#define N_NODES 100000
#define N_EDGES 3200000
#define F 256

#define BM 128
#define BN 128
#define BK 32

#define SCAN_NB ((N_NODES + 255) / 256)   // 391 blocks of 256

typedef __attribute__((ext_vector_type(8))) short short8;
typedef __attribute__((ext_vector_type(4))) float f32x4;

__device__ inline unsigned short f2bf(float f) {
    unsigned int u = __float_as_uint(f);
    unsigned int r = (u + 0x7fffu + ((u >> 16) & 1u)) >> 16;
    return (unsigned short)r;
}

// ---------------------------------------------------------------------------
// Weight transpose + convert: Wt[n][k] = bf16(W[k][n]). 256x256, tiny.
// ---------------------------------------------------------------------------
__global__ void wt_kernel(const float* __restrict__ W, unsigned short* __restrict__ Wt) {
    int idx = blockIdx.x * 256 + threadIdx.x;
    int n = idx >> 8;
    int k = idx & 255;
    Wt[n * 256 + k] = f2bf(W[k * 256 + n]);
}

// ---------------------------------------------------------------------------
// CSR build step 1: histogram of destination degrees.
// ---------------------------------------------------------------------------
__global__ __launch_bounds__(256)
void hist_kernel(const int* __restrict__ dst, int* __restrict__ counts) {
    for (int e = blockIdx.x * 256 + threadIdx.x; e < N_EDGES; e += gridDim.x * 256)
        atomicAdd(&counts[dst[e]], 1);
}

// ---------------------------------------------------------------------------
// CSR build step 2a: per-block exclusive scan (256 elems/block) + block totals
// ---------------------------------------------------------------------------
__global__ __launch_bounds__(256)
void scan1_kernel(const int* __restrict__ counts, int* __restrict__ row_start,
                  int* __restrict__ partials) {
    __shared__ int s[256];
    const int t = threadIdx.x;
    const int i = blockIdx.x * 256 + t;
    int v = (i < N_NODES) ? counts[i] : 0;
    s[t] = v;
    __syncthreads();
#pragma unroll
    for (int off = 1; off < 256; off <<= 1) {
        int x = (t >= off) ? s[t - off] : 0;
        __syncthreads();
        if (t >= off) s[t] += x;
        __syncthreads();
    }
    if (i < N_NODES) row_start[i] = s[t] - v;   // exclusive within block
    if (t == 255) partials[blockIdx.x] = s[t];  // block total
}

// ---------------------------------------------------------------------------
// CSR build step 2b: scan the 391 block totals (single block, 512 threads)
// ---------------------------------------------------------------------------
__global__ __launch_bounds__(512)
void scan2_kernel(int* __restrict__ partials) {
    __shared__ int s[512];
    const int t = threadIdx.x;
    int v = (t < SCAN_NB) ? partials[t] : 0;
    s[t] = v;
    __syncthreads();
#pragma unroll
    for (int off = 1; off < 512; off <<= 1) {
        int x = (t >= off) ? s[t - off] : 0;
        __syncthreads();
        if (t >= off) s[t] += x;
        __syncthreads();
    }
    if (t < SCAN_NB) partials[t] = s[t] - v;    // exclusive block offsets
}

// ---------------------------------------------------------------------------
// CSR build step 2c: add block offsets; init cursor = row_start.
// ---------------------------------------------------------------------------
__global__ __launch_bounds__(256)
void scan3_kernel(int* __restrict__ row_start, int* __restrict__ cursor,
                  const int* __restrict__ partials) {
    const int i = blockIdx.x * 256 + threadIdx.x;
    if (i < N_NODES) {
        int val = row_start[i] + partials[blockIdx.x];
        row_start[i] = val;
        cursor[i] = val;
    }
    if (i == 0) row_start[N_NODES] = N_EDGES;
}

// ---------------------------------------------------------------------------
// CSR build step 3: bucket-fill packed (src, val) records sorted by dst.
// ---------------------------------------------------------------------------
__global__ __launch_bounds__(256)
void fill_kernel(const int* __restrict__ src, const int* __restrict__ dst,
                 const float* __restrict__ val, int* __restrict__ cursor,
                 int2* __restrict__ recs) {
    for (int e = blockIdx.x * 256 + threadIdx.x; e < N_EDGES; e += gridDim.x * 256) {
        int d = dst[e];
        int pos = atomicAdd(&cursor[d], 1);
        recs[pos] = make_int2(src[e], __float_as_int(val[e]));
    }
}

// ---------------------------------------------------------------------------
// GEMM: out[n, 0:256] = input[n, :] @ W   (bf16 MFMA, fp32 accumulate)
// ---------------------------------------------------------------------------
__global__ __launch_bounds__(256, 2)
void gemm_kernel(const float* __restrict__ A,
                 const unsigned short* __restrict__ Wt,
                 float* __restrict__ out)
{
    __shared__ unsigned short As[BM * BK];
    __shared__ unsigned short Bs[BN * BK];

    const int tid   = threadIdx.x;
    const int lane  = tid & 63;
    const int wave  = tid >> 6;
    const int waveM = wave >> 1;
    const int waveN = wave & 1;
    const int rowBase = blockIdx.x * BM;
    const int bn      = blockIdx.y;

    f32x4 acc[4][4];
#pragma unroll
    for (int i = 0; i < 4; i++)
#pragma unroll
        for (int j = 0; j < 4; j++) acc[i][j] = (f32x4)0.0f;

    const int sr = tid >> 2;
    const int sk = (tid & 3) * 8;
    const int quad = lane >> 4;
    const int l16  = lane & 15;

    for (int kt = 0; kt < 8; kt++) {
        const int k0 = kt * BK;
#pragma unroll
        for (int p = 0; p < 2; p++) {
            const int r = p * 64 + sr;
            const int grow = rowBase + r;
            short8 av;
            if (grow < N_NODES) {
                const float4* pa = (const float4*)(A + (size_t)grow * 256 + k0 + sk);
                float4 f0 = pa[0];
                float4 f1 = pa[1];
                av[0] = (short)f2bf(f0.x); av[1] = (short)f2bf(f0.y);
                av[2] = (short)f2bf(f0.z); av[3] = (short)f2bf(f0.w);
                av[4] = (short)f2bf(f1.x); av[5] = (short)f2bf(f1.y);
                av[6] = (short)f2bf(f1.z); av[7] = (short)f2bf(f1.w);
            } else {
                av = (short8)0;
            }
            *(short8*)(&As[r * BK + sk]) = av;

            const uint4 wv = *(const uint4*)(Wt + (size_t)(bn * BN + r) * 256 + k0 + sk);
            *(uint4*)(&Bs[r * BK + sk]) = wv;
        }
        __syncthreads();

        short8 af[4], bfr[4];
#pragma unroll
        for (int i = 0; i < 4; i++)
            af[i] = *(const short8*)(&As[(waveM * 64 + i * 16 + l16) * BK + quad * 8]);
#pragma unroll
        for (int j = 0; j < 4; j++)
            bfr[j] = *(const short8*)(&Bs[(waveN * 64 + j * 16 + l16) * BK + quad * 8]);
#pragma unroll
        for (int i = 0; i < 4; i++)
#pragma unroll
            for (int j = 0; j < 4; j++)
                acc[i][j] = __builtin_amdgcn_mfma_f32_16x16x32_bf16(
                    af[i], bfr[j], acc[i][j], 0, 0, 0);
        __syncthreads();
    }

    const int colBase = bn * BN + waveN * 64;
#pragma unroll
    for (int i = 0; i < 4; i++) {
        const int row0 = rowBase + waveM * 64 + i * 16 + quad * 4;
#pragma unroll
        for (int j = 0; j < 4; j++) {
            const int col = colBase + j * 16 + l16;
#pragma unroll
            for (int r = 0; r < 4; r++) {
                const int row = row0 + r;
                if (row < N_NODES)
                    out[(size_t)row * 512 + col] = acc[i][j][r];
            }
        }
    }
}

// ---------------------------------------------------------------------------
// Gather: one wave per dst node. out[n, 256:512] = sum_e val_e * out[src_e, 0:256]
// Single writer per output row -> no atomics, no pre-zeroing needed.
// ---------------------------------------------------------------------------
__global__ __launch_bounds__(256)
void gather_kernel(const int* __restrict__ row_start,
                   const int2* __restrict__ recs,
                   float* __restrict__ out)
{
    const int n = blockIdx.x * 4 + (threadIdx.x >> 6);
    if (n >= N_NODES) return;
    const int lane = threadIdx.x & 63;

    const int beg = row_start[n];
    const int end = row_start[n + 1];

    float ax = 0.f, ay = 0.f, az = 0.f, aw = 0.f;

    int e = beg;
    for (; e + 1 < end; e += 2) {
        int2 r0 = recs[e];
        int2 r1 = recs[e + 1];
        const float4 x0 = *(const float4*)(out + (size_t)r0.x * 512 + lane * 4);
        const float4 x1 = *(const float4*)(out + (size_t)r1.x * 512 + lane * 4);
        const float v0 = __int_as_float(r0.y);
        const float v1 = __int_as_float(r1.y);
        ax += v0 * x0.x; ay += v0 * x0.y; az += v0 * x0.z; aw += v0 * x0.w;
        ax += v1 * x1.x; ay += v1 * x1.y; az += v1 * x1.z; aw += v1 * x1.w;
    }
    if (e < end) {
        int2 r0 = recs[e];
        const float4 x0 = *(const float4*)(out + (size_t)r0.x * 512 + lane * 4);
        const float v0 = __int_as_float(r0.y);
        ax += v0 * x0.x; ay += v0 * x0.y; az += v0 * x0.z; aw += v0 * x0.w;
    }

    float4 res = make_float4(ax, ay, az, aw);
    *(float4*)(out + (size_t)n * 512 + 256 + lane * 4) = res;
}

// ---------------------------------------------------------------------------
extern "C" void kernel_launch(void* const* d_in, const int* in_sizes, int n_in,
                              void* d_out, int out_size, void* d_ws, size_t ws_size,
                              hipStream_t stream)
{
    const float* input = (const float*)d_in[0];
    const int*   esrc  = (const int*)d_in[1];
    const int*   edst  = (const int*)d_in[2];
    const float* eval  = (const float*)d_in[3];
    const float* W     = (const float*)d_in[4];
    float* out = (float*)d_out;

    char* ws = (char*)d_ws;
    unsigned short* Wt  = (unsigned short*)(ws);             // 131072 B
    int* counts    = (int*)(ws + 131072);                    // 400000 B
    int* row_start = (int*)(ws + 532480);                    // 400004 B
    int* cursor    = (int*)(ws + 933888);                    // 400000 B
    int* partials  = (int*)(ws + 1334272);                   // 2048 B
    int2* recs     = (int2*)(ws + 1336320);                  // 25.6 MB

    // zero degree histogram (ws is poisoned 0xAA each launch)
    hipMemsetAsync(counts, 0, N_NODES * sizeof(int), stream);

    wt_kernel<<<256, 256, 0, stream>>>(W, Wt);
    hist_kernel<<<1024, 256, 0, stream>>>(edst, counts);
    scan1_kernel<<<SCAN_NB, 256, 0, stream>>>(counts, row_start, partials);
    scan2_kernel<<<1, 512, 0, stream>>>(partials);
    scan3_kernel<<<SCAN_NB, 256, 0, stream>>>(row_start, cursor, partials);
    fill_kernel<<<1024, 256, 0, stream>>>(esrc, edst, eval, cursor, recs);

    dim3 g((N_NODES + BM - 1) / BM, 2);
    gemm_kernel<<<g, 256, 0, stream>>>(input, Wt, out);

    gather_kernel<<<(N_NODES + 3) / 4, 256, 0, stream>>>(row_start, recs, out);
}

// Round 3
// 923.901 us; speedup vs baseline: 11.7697x; 1.1769x over previous
//
#include <hip/hip_runtime.h>

#define N_NODES 100000
#define N_EDGES 3200000
#define F 256

#define BM 128
#define BN 128
#define BK 32

#define SCAN_NB ((N_NODES + 255) / 256)   // 391 blocks of 256

typedef __attribute__((ext_vector_type(8))) short short8;
typedef __attribute__((ext_vector_type(4))) float f32x4;

__device__ inline unsigned short f2bf(float f) {
    unsigned int u = __float_as_uint(f);
    unsigned int r = (u + 0x7fffu + ((u >> 16) & 1u)) >> 16;
    return (unsigned short)r;
}

__device__ inline float bf2f(unsigned short b) {
    return __uint_as_float(((unsigned int)b) << 16);
}

// ---------------------------------------------------------------------------
// Weight transpose + convert: Wt[n][k] = bf16(W[k][n]). 256x256, tiny.
// ---------------------------------------------------------------------------
__global__ void wt_kernel(const float* __restrict__ W, unsigned short* __restrict__ Wt) {
    int idx = blockIdx.x * 256 + threadIdx.x;
    int n = idx >> 8;
    int k = idx & 255;
    Wt[n * 256 + k] = f2bf(W[k * 256 + n]);
}

// ---------------------------------------------------------------------------
// CSR build step 1: histogram of destination degrees.
// ---------------------------------------------------------------------------
__global__ __launch_bounds__(256)
void hist_kernel(const int* __restrict__ dst, int* __restrict__ counts) {
    for (int e = blockIdx.x * 256 + threadIdx.x; e < N_EDGES; e += gridDim.x * 256)
        atomicAdd(&counts[dst[e]], 1);
}

// ---------------------------------------------------------------------------
// CSR build step 2a: per-block exclusive scan (256 elems/block) + block totals
// ---------------------------------------------------------------------------
__global__ __launch_bounds__(256)
void scan1_kernel(const int* __restrict__ counts, int* __restrict__ row_start,
                  int* __restrict__ partials) {
    __shared__ int s[256];
    const int t = threadIdx.x;
    const int i = blockIdx.x * 256 + t;
    int v = (i < N_NODES) ? counts[i] : 0;
    s[t] = v;
    __syncthreads();
#pragma unroll
    for (int off = 1; off < 256; off <<= 1) {
        int x = (t >= off) ? s[t - off] : 0;
        __syncthreads();
        if (t >= off) s[t] += x;
        __syncthreads();
    }
    if (i < N_NODES) row_start[i] = s[t] - v;
    if (t == 255) partials[blockIdx.x] = s[t];
}

// ---------------------------------------------------------------------------
// CSR build step 2b: scan the 391 block totals (single block, 512 threads)
// ---------------------------------------------------------------------------
__global__ __launch_bounds__(512)
void scan2_kernel(int* __restrict__ partials) {
    __shared__ int s[512];
    const int t = threadIdx.x;
    int v = (t < SCAN_NB) ? partials[t] : 0;
    s[t] = v;
    __syncthreads();
#pragma unroll
    for (int off = 1; off < 512; off <<= 1) {
        int x = (t >= off) ? s[t - off] : 0;
        __syncthreads();
        if (t >= off) s[t] += x;
        __syncthreads();
    }
    if (t < SCAN_NB) partials[t] = s[t] - v;
}

// ---------------------------------------------------------------------------
// CSR build step 2c: add block offsets; init cursor = row_start.
// ---------------------------------------------------------------------------
__global__ __launch_bounds__(256)
void scan3_kernel(int* __restrict__ row_start, int* __restrict__ cursor,
                  const int* __restrict__ partials) {
    const int i = blockIdx.x * 256 + threadIdx.x;
    if (i < N_NODES) {
        int val = row_start[i] + partials[blockIdx.x];
        row_start[i] = val;
        cursor[i] = val;
    }
    if (i == 0) row_start[N_NODES] = N_EDGES;
}

// ---------------------------------------------------------------------------
// CSR build step 3: bucket-fill packed (src, val) records sorted by dst.
// ---------------------------------------------------------------------------
__global__ __launch_bounds__(256)
void fill_kernel(const int* __restrict__ src, const int* __restrict__ dst,
                 const float* __restrict__ val, int* __restrict__ cursor,
                 int2* __restrict__ recs) {
    for (int e = blockIdx.x * 256 + threadIdx.x; e < N_EDGES; e += gridDim.x * 256) {
        int d = dst[e];
        int pos = atomicAdd(&cursor[d], 1);
        recs[pos] = make_int2(src[e], __float_as_int(val[e]));
    }
}

// ---------------------------------------------------------------------------
// GEMM: out[n, 0:256] = input[n, :] @ W  (fp32 result) and a compact bf16
// copy ftb[n][256] for the gather stage (keeps its random-read set at 51 MB,
// fully L3-resident, and halves gather read volume).
// ---------------------------------------------------------------------------
__global__ __launch_bounds__(256, 2)
void gemm_kernel(const float* __restrict__ A,
                 const unsigned short* __restrict__ Wt,
                 float* __restrict__ out,
                 unsigned short* __restrict__ ftb)
{
    __shared__ unsigned short As[BM * BK];
    __shared__ unsigned short Bs[BN * BK];

    const int tid   = threadIdx.x;
    const int lane  = tid & 63;
    const int wave  = tid >> 6;
    const int waveM = wave >> 1;
    const int waveN = wave & 1;
    const int rowBase = blockIdx.x * BM;
    const int bn      = blockIdx.y;

    f32x4 acc[4][4];
#pragma unroll
    for (int i = 0; i < 4; i++)
#pragma unroll
        for (int j = 0; j < 4; j++) acc[i][j] = (f32x4)0.0f;

    const int sr = tid >> 2;
    const int sk = (tid & 3) * 8;
    const int quad = lane >> 4;
    const int l16  = lane & 15;

    for (int kt = 0; kt < 8; kt++) {
        const int k0 = kt * BK;
#pragma unroll
        for (int p = 0; p < 2; p++) {
            const int r = p * 64 + sr;
            const int grow = rowBase + r;
            short8 av;
            if (grow < N_NODES) {
                const float4* pa = (const float4*)(A + (size_t)grow * 256 + k0 + sk);
                float4 f0 = pa[0];
                float4 f1 = pa[1];
                av[0] = (short)f2bf(f0.x); av[1] = (short)f2bf(f0.y);
                av[2] = (short)f2bf(f0.z); av[3] = (short)f2bf(f0.w);
                av[4] = (short)f2bf(f1.x); av[5] = (short)f2bf(f1.y);
                av[6] = (short)f2bf(f1.z); av[7] = (short)f2bf(f1.w);
            } else {
                av = (short8)0;
            }
            *(short8*)(&As[r * BK + sk]) = av;

            const uint4 wv = *(const uint4*)(Wt + (size_t)(bn * BN + r) * 256 + k0 + sk);
            *(uint4*)(&Bs[r * BK + sk]) = wv;
        }
        __syncthreads();

        short8 af[4], bfr[4];
#pragma unroll
        for (int i = 0; i < 4; i++)
            af[i] = *(const short8*)(&As[(waveM * 64 + i * 16 + l16) * BK + quad * 8]);
#pragma unroll
        for (int j = 0; j < 4; j++)
            bfr[j] = *(const short8*)(&Bs[(waveN * 64 + j * 16 + l16) * BK + quad * 8]);
#pragma unroll
        for (int i = 0; i < 4; i++)
#pragma unroll
            for (int j = 0; j < 4; j++)
                acc[i][j] = __builtin_amdgcn_mfma_f32_16x16x32_bf16(
                    af[i], bfr[j], acc[i][j], 0, 0, 0);
        __syncthreads();
    }

    const int colBase = bn * BN + waveN * 64;
#pragma unroll
    for (int i = 0; i < 4; i++) {
        const int row0 = rowBase + waveM * 64 + i * 16 + quad * 4;
#pragma unroll
        for (int j = 0; j < 4; j++) {
            const int col = colBase + j * 16 + l16;
#pragma unroll
            for (int r = 0; r < 4; r++) {
                const int row = row0 + r;
                if (row < N_NODES) {
                    float v = acc[i][j][r];
                    out[(size_t)row * 512 + col] = v;
                    ftb[(size_t)row * 256 + col] = f2bf(v);
                }
            }
        }
    }
}

// ---------------------------------------------------------------------------
// Gather: one wave per dst node. out[n, 256:512] = sum_e val_e * ftb[src_e]
// bf16 source rows (512 B each): lane reads ushort4 (8 B), fp32 accumulate.
// Single writer per output row -> no atomics, no pre-zeroing.
// ---------------------------------------------------------------------------
__global__ __launch_bounds__(256)
void gather_kernel(const int* __restrict__ row_start,
                   const int2* __restrict__ recs,
                   const unsigned short* __restrict__ ftb,
                   float* __restrict__ out)
{
    const int n = blockIdx.x * 4 + (threadIdx.x >> 6);
    if (n >= N_NODES) return;
    const int lane = threadIdx.x & 63;

    const int beg = row_start[n];
    const int end = row_start[n + 1];

    float ax = 0.f, ay = 0.f, az = 0.f, aw = 0.f;

    int e = beg;
    for (; e + 1 < end; e += 2) {
        int2 r0 = recs[e];
        int2 r1 = recs[e + 1];
        ushort4 u0 = *(const ushort4*)(ftb + (size_t)r0.x * 256 + lane * 4);
        ushort4 u1 = *(const ushort4*)(ftb + (size_t)r1.x * 256 + lane * 4);
        const float v0 = __int_as_float(r0.y);
        const float v1 = __int_as_float(r1.y);
        ax += v0 * bf2f(u0.x); ay += v0 * bf2f(u0.y);
        az += v0 * bf2f(u0.z); aw += v0 * bf2f(u0.w);
        ax += v1 * bf2f(u1.x); ay += v1 * bf2f(u1.y);
        az += v1 * bf2f(u1.z); aw += v1 * bf2f(u1.w);
    }
    if (e < end) {
        int2 r0 = recs[e];
        ushort4 u0 = *(const ushort4*)(ftb + (size_t)r0.x * 256 + lane * 4);
        const float v0 = __int_as_float(r0.y);
        ax += v0 * bf2f(u0.x); ay += v0 * bf2f(u0.y);
        az += v0 * bf2f(u0.z); aw += v0 * bf2f(u0.w);
    }

    float4 res = make_float4(ax, ay, az, aw);
    *(float4*)(out + (size_t)n * 512 + 256 + lane * 4) = res;
}

// ---------------------------------------------------------------------------
extern "C" void kernel_launch(void* const* d_in, const int* in_sizes, int n_in,
                              void* d_out, int out_size, void* d_ws, size_t ws_size,
                              hipStream_t stream)
{
    const float* input = (const float*)d_in[0];
    const int*   esrc  = (const int*)d_in[1];
    const int*   edst  = (const int*)d_in[2];
    const float* eval  = (const float*)d_in[3];
    const float* W     = (const float*)d_in[4];
    float* out = (float*)d_out;

    char* ws = (char*)d_ws;
    unsigned short* Wt  = (unsigned short*)(ws);             // 131072 B
    int* counts    = (int*)(ws + 131072);                    // 400000 B
    int* row_start = (int*)(ws + 532480);                    // 400004 B
    int* cursor    = (int*)(ws + 933888);                    // 400000 B
    int* partials  = (int*)(ws + 1334272);                   // 2048 B
    int2* recs     = (int2*)(ws + 1336320);                  // 25.6 MB
    unsigned short* ftb = (unsigned short*)(ws + 1336320 + (size_t)N_EDGES * 8); // 51.2 MB

    hipMemsetAsync(counts, 0, N_NODES * sizeof(int), stream);

    wt_kernel<<<256, 256, 0, stream>>>(W, Wt);
    hist_kernel<<<1024, 256, 0, stream>>>(edst, counts);
    scan1_kernel<<<SCAN_NB, 256, 0, stream>>>(counts, row_start, partials);
    scan2_kernel<<<1, 512, 0, stream>>>(partials);
    scan3_kernel<<<SCAN_NB, 256, 0, stream>>>(row_start, cursor, partials);
    fill_kernel<<<1024, 256, 0, stream>>>(esrc, edst, eval, cursor, recs);

    dim3 g((N_NODES + BM - 1) / BM, 2);
    gemm_kernel<<<g, 256, 0, stream>>>(input, Wt, out, ftb);

    gather_kernel<<<(N_NODES + 3) / 4, 256, 0, stream>>>(row_start, recs, ftb, out);
}

// Round 4
// 766.686 us; speedup vs baseline: 14.1832x; 1.2051x over previous
//
#include <hip/hip_runtime.h>

#define N_NODES 100000
#define N_EDGES 3200000
#define F 256

#define BM 128
#define BN 128
#define BK 32

#define SCAN_NB ((N_NODES + 255) / 256)   // 391 blocks of 256
#define EDGE_NB (N_EDGES / 256)           // 12500 blocks, exact

typedef __attribute__((ext_vector_type(8))) short short8;
typedef __attribute__((ext_vector_type(4))) float f32x4;

__device__ inline unsigned short f2bf(float f) {
    unsigned int u = __float_as_uint(f);
    unsigned int r = (u + 0x7fffu + ((u >> 16) & 1u)) >> 16;
    return (unsigned short)r;
}

__device__ inline float bf2f(unsigned short b) {
    return __uint_as_float(((unsigned int)b) << 16);
}

// ---------------------------------------------------------------------------
// Weight transpose + convert: Wt[n][k] = bf16(W[k][n]). 256x256, tiny.
// ---------------------------------------------------------------------------
__global__ void wt_kernel(const float* __restrict__ W, unsigned short* __restrict__ Wt) {
    int idx = blockIdx.x * 256 + threadIdx.x;
    int n = idx >> 8;
    int k = idx & 255;
    Wt[n * 256 + k] = f2bf(W[k * 256 + n]);
}

// ---------------------------------------------------------------------------
// CSR build step 1: degree histogram AND per-edge rank (the atomic's return
// value). rank is what lets fill_kernel run atomic-free. One thread per edge.
// ---------------------------------------------------------------------------
__global__ __launch_bounds__(256)
void rank_hist_kernel(const int* __restrict__ dst, int* __restrict__ counts,
                      unsigned short* __restrict__ rank) {
    const int e = blockIdx.x * 256 + threadIdx.x;
    rank[e] = (unsigned short)atomicAdd(&counts[dst[e]], 1);
}

// ---------------------------------------------------------------------------
// CSR build step 2a: per-block exclusive scan (256 elems/block) + block totals
// ---------------------------------------------------------------------------
__global__ __launch_bounds__(256)
void scan1_kernel(const int* __restrict__ counts, int* __restrict__ row_start,
                  int* __restrict__ partials) {
    __shared__ int s[256];
    const int t = threadIdx.x;
    const int i = blockIdx.x * 256 + t;
    int v = (i < N_NODES) ? counts[i] : 0;
    s[t] = v;
    __syncthreads();
#pragma unroll
    for (int off = 1; off < 256; off <<= 1) {
        int x = (t >= off) ? s[t - off] : 0;
        __syncthreads();
        if (t >= off) s[t] += x;
        __syncthreads();
    }
    if (i < N_NODES) row_start[i] = s[t] - v;
    if (t == 255) partials[blockIdx.x] = s[t];
}

// ---------------------------------------------------------------------------
// CSR build step 2b: scan the 391 block totals (single block, 512 threads)
// ---------------------------------------------------------------------------
__global__ __launch_bounds__(512)
void scan2_kernel(int* __restrict__ partials) {
    __shared__ int s[512];
    const int t = threadIdx.x;
    int v = (t < SCAN_NB) ? partials[t] : 0;
    s[t] = v;
    __syncthreads();
#pragma unroll
    for (int off = 1; off < 512; off <<= 1) {
        int x = (t >= off) ? s[t - off] : 0;
        __syncthreads();
        if (t >= off) s[t] += x;
        __syncthreads();
    }
    if (t < SCAN_NB) partials[t] = s[t] - v;
}

// ---------------------------------------------------------------------------
// CSR build step 2c: add block offsets.
// ---------------------------------------------------------------------------
__global__ __launch_bounds__(256)
void scan3_kernel(int* __restrict__ row_start, const int* __restrict__ partials) {
    const int i = blockIdx.x * 256 + threadIdx.x;
    if (i < N_NODES)
        row_start[i] += partials[blockIdx.x];
    if (i == 0) row_start[N_NODES] = N_EDGES;
}

// ---------------------------------------------------------------------------
// CSR build step 3: place packed (src, val) records at row_start[d] + rank[e].
// No atomics: pure loads + one scattered 8B store per edge.
// ---------------------------------------------------------------------------
__global__ __launch_bounds__(256)
void fill_kernel(const int* __restrict__ src, const int* __restrict__ dst,
                 const float* __restrict__ val,
                 const int* __restrict__ row_start,
                 const unsigned short* __restrict__ rank,
                 int2* __restrict__ recs) {
    const int e = blockIdx.x * 256 + threadIdx.x;
    const int d = dst[e];
    const int pos = row_start[d] + (int)rank[e];
    recs[pos] = make_int2(src[e], __float_as_int(val[e]));
}

// ---------------------------------------------------------------------------
// GEMM: out[n, 0:256] = input[n, :] @ W  (fp32 result) and a compact bf16
// copy ftb[n][256] for the gather stage (51 MB, L3-resident random-read set).
// ---------------------------------------------------------------------------
__global__ __launch_bounds__(256, 2)
void gemm_kernel(const float* __restrict__ A,
                 const unsigned short* __restrict__ Wt,
                 float* __restrict__ out,
                 unsigned short* __restrict__ ftb)
{
    __shared__ unsigned short As[BM * BK];
    __shared__ unsigned short Bs[BN * BK];

    const int tid   = threadIdx.x;
    const int lane  = tid & 63;
    const int wave  = tid >> 6;
    const int waveM = wave >> 1;
    const int waveN = wave & 1;
    const int rowBase = blockIdx.x * BM;
    const int bn      = blockIdx.y;

    f32x4 acc[4][4];
#pragma unroll
    for (int i = 0; i < 4; i++)
#pragma unroll
        for (int j = 0; j < 4; j++) acc[i][j] = (f32x4)0.0f;

    const int sr = tid >> 2;
    const int sk = (tid & 3) * 8;
    const int quad = lane >> 4;
    const int l16  = lane & 15;

    for (int kt = 0; kt < 8; kt++) {
        const int k0 = kt * BK;
#pragma unroll
        for (int p = 0; p < 2; p++) {
            const int r = p * 64 + sr;
            const int grow = rowBase + r;
            short8 av;
            if (grow < N_NODES) {
                const float4* pa = (const float4*)(A + (size_t)grow * 256 + k0 + sk);
                float4 f0 = pa[0];
                float4 f1 = pa[1];
                av[0] = (short)f2bf(f0.x); av[1] = (short)f2bf(f0.y);
                av[2] = (short)f2bf(f0.z); av[3] = (short)f2bf(f0.w);
                av[4] = (short)f2bf(f1.x); av[5] = (short)f2bf(f1.y);
                av[6] = (short)f2bf(f1.z); av[7] = (short)f2bf(f1.w);
            } else {
                av = (short8)0;
            }
            *(short8*)(&As[r * BK + sk]) = av;

            const uint4 wv = *(const uint4*)(Wt + (size_t)(bn * BN + r) * 256 + k0 + sk);
            *(uint4*)(&Bs[r * BK + sk]) = wv;
        }
        __syncthreads();

        short8 af[4], bfr[4];
#pragma unroll
        for (int i = 0; i < 4; i++)
            af[i] = *(const short8*)(&As[(waveM * 64 + i * 16 + l16) * BK + quad * 8]);
#pragma unroll
        for (int j = 0; j < 4; j++)
            bfr[j] = *(const short8*)(&Bs[(waveN * 64 + j * 16 + l16) * BK + quad * 8]);
#pragma unroll
        for (int i = 0; i < 4; i++)
#pragma unroll
            for (int j = 0; j < 4; j++)
                acc[i][j] = __builtin_amdgcn_mfma_f32_16x16x32_bf16(
                    af[i], bfr[j], acc[i][j], 0, 0, 0);
        __syncthreads();
    }

    const int colBase = bn * BN + waveN * 64;
#pragma unroll
    for (int i = 0; i < 4; i++) {
        const int row0 = rowBase + waveM * 64 + i * 16 + quad * 4;
#pragma unroll
        for (int j = 0; j < 4; j++) {
            const int col = colBase + j * 16 + l16;
#pragma unroll
            for (int r = 0; r < 4; r++) {
                const int row = row0 + r;
                if (row < N_NODES) {
                    float v = acc[i][j][r];
                    out[(size_t)row * 512 + col] = v;
                    ftb[(size_t)row * 256 + col] = f2bf(v);
                }
            }
        }
    }
}

// ---------------------------------------------------------------------------
// Gather: one wave per dst node. out[n, 256:512] = sum_e val_e * ftb[src_e]
// 4-edge unroll: 4 outstanding 512B row reads per wave. Single writer per row.
// ---------------------------------------------------------------------------
__global__ __launch_bounds__(256)
void gather_kernel(const int* __restrict__ row_start,
                   const int2* __restrict__ recs,
                   const unsigned short* __restrict__ ftb,
                   float* __restrict__ out)
{
    const int n = blockIdx.x * 4 + (threadIdx.x >> 6);
    if (n >= N_NODES) return;
    const int lane = threadIdx.x & 63;

    const int beg = row_start[n];
    const int end = row_start[n + 1];

    float ax = 0.f, ay = 0.f, az = 0.f, aw = 0.f;

    int e = beg;
    for (; e + 3 < end; e += 4) {
        int2 r0 = recs[e];
        int2 r1 = recs[e + 1];
        int2 r2 = recs[e + 2];
        int2 r3 = recs[e + 3];
        ushort4 u0 = *(const ushort4*)(ftb + (size_t)r0.x * 256 + lane * 4);
        ushort4 u1 = *(const ushort4*)(ftb + (size_t)r1.x * 256 + lane * 4);
        ushort4 u2 = *(const ushort4*)(ftb + (size_t)r2.x * 256 + lane * 4);
        ushort4 u3 = *(const ushort4*)(ftb + (size_t)r3.x * 256 + lane * 4);
        const float v0 = __int_as_float(r0.y);
        const float v1 = __int_as_float(r1.y);
        const float v2 = __int_as_float(r2.y);
        const float v3 = __int_as_float(r3.y);
        ax += v0 * bf2f(u0.x); ay += v0 * bf2f(u0.y);
        az += v0 * bf2f(u0.z); aw += v0 * bf2f(u0.w);
        ax += v1 * bf2f(u1.x); ay += v1 * bf2f(u1.y);
        az += v1 * bf2f(u1.z); aw += v1 * bf2f(u1.w);
        ax += v2 * bf2f(u2.x); ay += v2 * bf2f(u2.y);
        az += v2 * bf2f(u2.z); aw += v2 * bf2f(u2.w);
        ax += v3 * bf2f(u3.x); ay += v3 * bf2f(u3.y);
        az += v3 * bf2f(u3.z); aw += v3 * bf2f(u3.w);
    }
    for (; e < end; e++) {
        int2 r0 = recs[e];
        ushort4 u0 = *(const ushort4*)(ftb + (size_t)r0.x * 256 + lane * 4);
        const float v0 = __int_as_float(r0.y);
        ax += v0 * bf2f(u0.x); ay += v0 * bf2f(u0.y);
        az += v0 * bf2f(u0.z); aw += v0 * bf2f(u0.w);
    }

    float4 res = make_float4(ax, ay, az, aw);
    *(float4*)(out + (size_t)n * 512 + 256 + lane * 4) = res;
}

// ---------------------------------------------------------------------------
extern "C" void kernel_launch(void* const* d_in, const int* in_sizes, int n_in,
                              void* d_out, int out_size, void* d_ws, size_t ws_size,
                              hipStream_t stream)
{
    const float* input = (const float*)d_in[0];
    const int*   esrc  = (const int*)d_in[1];
    const int*   edst  = (const int*)d_in[2];
    const float* eval  = (const float*)d_in[3];
    const float* W     = (const float*)d_in[4];
    float* out = (float*)d_out;

    char* ws = (char*)d_ws;
    unsigned short* Wt   = (unsigned short*)(ws);              // 131072 B
    int* counts          = (int*)(ws + 131072);                // 400000 B
    int* row_start       = (int*)(ws + 532480);                // 400004 B
    unsigned short* rank = (unsigned short*)(ws + 933888);     // 6.4e6 B
    int* partials        = (int*)(ws + 7334912);               // 2048 B
    int2* recs           = (int2*)(ws + 7337984);              // 25.6 MB
    unsigned short* ftb  = (unsigned short*)(ws + 7337984 + (size_t)N_EDGES * 8); // 51.2 MB

    hipMemsetAsync(counts, 0, N_NODES * sizeof(int), stream);

    wt_kernel<<<256, 256, 0, stream>>>(W, Wt);
    rank_hist_kernel<<<EDGE_NB, 256, 0, stream>>>(edst, counts, rank);
    scan1_kernel<<<SCAN_NB, 256, 0, stream>>>(counts, row_start, partials);
    scan2_kernel<<<1, 512, 0, stream>>>(partials);
    scan3_kernel<<<SCAN_NB, 256, 0, stream>>>(row_start, partials);
    fill_kernel<<<EDGE_NB, 256, 0, stream>>>(esrc, edst, eval, row_start, rank, recs);

    dim3 g((N_NODES + BM - 1) / BM, 2);
    gemm_kernel<<<g, 256, 0, stream>>>(input, Wt, out, ftb);

    gather_kernel<<<(N_NODES + 3) / 4, 256, 0, stream>>>(row_start, recs, ftb, out);
}